// Round 1
// baseline (359.432 us; speedup 1.0000x reference)
//
#include <hip/hip_runtime.h>
#include <hip/hip_bf16.h>

// CTC greedy search:  logits (T,N,V) fp32, in_lens (N) int32.
// Outputs (all fp32, concatenated): max_total (N), paths (T,N), out_lens (N).

#define WAVE 64

// ---------------- Kernel 1: per-(t,n) row logsumexp-max + argmax -------------
// One wave per row of V elements. V = CH*256 held in registers (CH float4 per
// lane) so HBM is touched exactly once.  Results stored TRANSPOSED:
// rmax[n*T + t], rarg[n*T + t]  (row = t*N + n  ->  t = row/N, n = row%N).
template <int CH>
__global__ __launch_bounds__(256) void row_lse_kernel(
    const float* __restrict__ logits,
    float* __restrict__ rmaxT, int* __restrict__ rargT,
    int T, int N, int rows) {
  const int lane = threadIdx.x & (WAVE - 1);
  const int row  = blockIdx.x * (blockDim.x >> 6) + (threadIdx.x >> 6);
  if (row >= rows) return;
  const int V = CH * 256;
  const float* p = logits + (size_t)row * V;

  float m = -3.4e38f;
  int   mi = 0;
  float4 v[CH];
#pragma unroll
  for (int c = 0; c < CH; ++c) {
    const int idx = c * 256 + lane * 4;
    v[c] = *(const float4*)(p + idx);
    if (v[c].x > m) { m = v[c].x; mi = idx; }
    if (v[c].y > m) { m = v[c].y; mi = idx + 1; }
    if (v[c].z > m) { m = v[c].z; mi = idx + 2; }
    if (v[c].w > m) { m = v[c].w; mi = idx + 3; }
  }
  // wave reduce: max value, first (lowest) index on ties
#pragma unroll
  for (int off = 32; off; off >>= 1) {
    const float om = __shfl_down(m, off);
    const int   oi = __shfl_down(mi, off);
    if (om > m || (om == m && oi < mi)) { m = om; mi = oi; }
  }
  m = __shfl(m, 0);  // broadcast row max to all lanes

  float s = 0.f;
#pragma unroll
  for (int c = 0; c < CH; ++c)
    s += __expf(v[c].x - m) + __expf(v[c].y - m) +
         __expf(v[c].z - m) + __expf(v[c].w - m);
#pragma unroll
  for (int off = 32; off; off >>= 1) s += __shfl_down(s, off);

  if (lane == 0) {
    const int t = row / N, n = row % N;         // N=32 -> cheap
    // max(log_softmax) = max - lse = -log(sum exp(x - max))
    rmaxT[(size_t)n * T + t] = -__logf(s);
    rargT[(size_t)n * T + t] = mi;
  }
}

// Generic fallback (any V): two passes over the row via cache.
__global__ __launch_bounds__(256) void row_lse_generic(
    const float* __restrict__ logits,
    float* __restrict__ rmaxT, int* __restrict__ rargT,
    int T, int N, int V, int rows) {
  const int lane = threadIdx.x & (WAVE - 1);
  const int row  = blockIdx.x * (blockDim.x >> 6) + (threadIdx.x >> 6);
  if (row >= rows) return;
  const float* p = logits + (size_t)row * V;

  float m = -3.4e38f; int mi = 0;
  for (int i = lane; i < V; i += WAVE) {
    const float x = p[i];
    if (x > m) { m = x; mi = i; }
  }
  for (int off = 32; off; off >>= 1) {
    const float om = __shfl_down(m, off);
    const int   oi = __shfl_down(mi, off);
    if (om > m || (om == m && oi < mi)) { m = om; mi = oi; }
  }
  m = __shfl(m, 0);
  float s = 0.f;
  for (int i = lane; i < V; i += WAVE) s += __expf(p[i] - m);
  for (int off = 32; off; off >>= 1) s += __shfl_down(s, off);
  if (lane == 0) {
    const int t = row / N, n = row % N;
    rmaxT[(size_t)n * T + t] = -__logf(s);
    rargT[(size_t)n * T + t] = mi;
  }
}

// ---------------- Kernel 2: per-n dedup + compaction + sums ------------------
#define CB 256
__global__ __launch_bounds__(CB) void ctc_compact_kernel(
    const float* __restrict__ rmaxT, const int* __restrict__ rargT,
    const int* __restrict__ in_lens, float* __restrict__ out,
    int T, int N, int V) {
  const int n = blockIdx.x;
  const int tid = threadIdx.x;
  const int L = in_lens[n];
  const int blank = V - 1;            // (-1 + V) % V
  const int items = (T + CB - 1) / CB;
  const int t0 = tid * items;

  float* out_total = out;
  float* out_paths = out + N;                    // (T, N) layout
  float* out_lens  = out + N + (size_t)T * N;

  const float* rm = rmaxT + (size_t)n * T;
  const int*   ra = rargT + (size_t)n * T;

  int   cnt = 0;
  float sum = 0.f;
  for (int i = 0; i < items; ++i) {
    const int t = t0 + i;
    if (t >= T) break;
    const int a = ra[t];
    bool keep = (t < L) && (a != blank);
    if (keep && t > 0) keep = (a != ra[t - 1]);
    cnt += keep ? 1 : 0;
    if (t < L) sum += rm[t];
    out_paths[(size_t)t * N + n] = (float)a;     // phase 1: original argmax
  }

  __shared__ int   s_cnt[CB];
  __shared__ float s_sum[CB];
  s_cnt[tid] = cnt;
  s_sum[tid] = sum;
  __syncthreads();
  // inclusive Hillis-Steele scan (cnt) / reduction (sum rides along)
  for (int off = 1; off < CB; off <<= 1) {
    const int   c  = (tid >= off) ? s_cnt[tid - off] : 0;
    const float sv = (tid >= off) ? s_sum[tid - off] : 0.f;
    __syncthreads();
    s_cnt[tid] += c;
    s_sum[tid] += sv;
    __syncthreads();
  }
  const int prefix = s_cnt[tid] - cnt;           // exclusive
  if (tid == 0) {
    out_total[n] = s_sum[CB - 1];
    out_lens[n]  = (float)s_cnt[CB - 1];
  }
  __syncthreads();  // phase-1 global writes by all threads drained (vmcnt(0)+barrier)

  // phase 2: scatter kept tokens into compacted prefix
  int pos = prefix;
  for (int i = 0; i < items; ++i) {
    const int t = t0 + i;
    if (t >= T) break;
    const int a = ra[t];
    bool keep = (t < L) && (a != blank);
    if (keep && t > 0) keep = (a != ra[t - 1]);
    if (keep) {
      out_paths[(size_t)pos * N + n] = (float)a;
      ++pos;
    }
  }
}

extern "C" void kernel_launch(void* const* d_in, const int* in_sizes, int n_in,
                              void* d_out, int out_size, void* d_ws, size_t ws_size,
                              hipStream_t stream) {
  const float* logits = (const float*)d_in[0];
  const int* in_lens  = (const int*)d_in[1];
  float* out = (float*)d_out;

  const int N = in_sizes[1];
  const int T = (out_size - 2 * N) / N;          // out = N + T*N + N
  const long long total = in_sizes[0];
  const int V = (int)(total / ((long long)T * N));
  const int rows = T * N;

  float* rmaxT = (float*)d_ws;
  int*   rargT = (int*)((char*)d_ws + (size_t)rows * sizeof(float));

  const int wavesPerBlock = 4;                   // 256 threads
  const int grid1 = (rows + wavesPerBlock - 1) / wavesPerBlock;

  if (V == 1024) {
    row_lse_kernel<4><<<grid1, 256, 0, stream>>>(logits, rmaxT, rargT, T, N, rows);
  } else if (V == 512) {
    row_lse_kernel<2><<<grid1, 256, 0, stream>>>(logits, rmaxT, rargT, T, N, rows);
  } else if (V == 2048) {
    row_lse_kernel<8><<<grid1, 256, 0, stream>>>(logits, rmaxT, rargT, T, N, rows);
  } else {
    row_lse_generic<<<grid1, 256, 0, stream>>>(logits, rmaxT, rargT, T, N, V, rows);
  }

  ctc_compact_kernel<<<N, CB, 0, stream>>>(rmaxT, rargT, in_lens, out, T, N, V);
}

// Round 3
// 335.077 us; speedup vs baseline: 1.0727x; 1.0727x over previous
//
#include <hip/hip_runtime.h>
#include <hip/hip_bf16.h>

// CTC greedy search:  logits (T,N,V) fp32, in_lens (N) int32.
// Outputs (all fp32, concatenated): max_total (N), paths (T,N), out_lens (N).

#define WAVE 64

typedef float nvec4 __attribute__((ext_vector_type(4)));  // builtin-compatible

// ---------------- Kernel 1: per-(t,n) row logsumexp-max + argmax -------------
// One wave per row of V elements. V = CH*256 held in registers (CH nvec4 per
// lane) so HBM is touched exactly once.  Results stored TRANSPOSED for
// kernel 2: rmaxT[n*T + t], rargT[n*T + t]  (row = t*N + n).
// Additionally writes the default path value out_paths[row] = argmax (row is
// exactly the flat (T,N) index), coalesced via LDS across the block's 4 waves.
template <int CH>
__global__ __launch_bounds__(256) void row_lse_kernel(
    const float* __restrict__ logits,
    float* __restrict__ rmaxT, int* __restrict__ rargT,
    float* __restrict__ out_paths,
    int T, int N, int rows) {
  const int lane = threadIdx.x & (WAVE - 1);
  const int w    = threadIdx.x >> 6;            // wave id in block (0..3)
  const int row  = blockIdx.x * 4 + w;
  const bool active = row < rows;
  const int V = CH * 256;
  const float* p = logits + (size_t)(active ? row : 0) * V;
  const nvec4* p4 = (const nvec4*)p;

  float m = -3.4e38f;
  int   mi = 0;
  nvec4 v[CH];
#pragma unroll
  for (int c = 0; c < CH; ++c) {
    // streamed once -> nontemporal, keep L2 for the small intermediates
    v[c] = __builtin_nontemporal_load(p4 + c * 64 + lane);
    const int idx = c * 256 + lane * 4;
    if (v[c].x > m) { m = v[c].x; mi = idx; }
    if (v[c].y > m) { m = v[c].y; mi = idx + 1; }
    if (v[c].z > m) { m = v[c].z; mi = idx + 2; }
    if (v[c].w > m) { m = v[c].w; mi = idx + 3; }
  }
  // wave reduce: max value, first (lowest) index on ties
#pragma unroll
  for (int off = 32; off; off >>= 1) {
    const float om = __shfl_down(m, off);
    const int   oi = __shfl_down(mi, off);
    if (om > m || (om == m && oi < mi)) { m = om; mi = oi; }
  }
  m = __shfl(m, 0);  // broadcast row max to all lanes

  float s = 0.f;
#pragma unroll
  for (int c = 0; c < CH; ++c)
    s += __expf(v[c].x - m) + __expf(v[c].y - m) +
         __expf(v[c].z - m) + __expf(v[c].w - m);
#pragma unroll
  for (int off = 32; off; off >>= 1) s += __shfl_down(s, off);

  __shared__ float s_path[4];
  if (lane == 0 && active) {
    const int t = row / N, n = row % N;
    // max(log_softmax) = max - lse = -log(sum exp(x - max))
    rmaxT[(size_t)n * T + t] = -__logf(s);
    rargT[(size_t)n * T + t] = mi;
    s_path[w] = (float)mi;
  }
  __syncthreads();
  if (threadIdx.x < 4) {
    const int r = blockIdx.x * 4 + threadIdx.x;
    if (r < rows) out_paths[r] = s_path[threadIdx.x];
  }
}

// Generic fallback (any V): strided row scan.
__global__ __launch_bounds__(256) void row_lse_generic(
    const float* __restrict__ logits,
    float* __restrict__ rmaxT, int* __restrict__ rargT,
    float* __restrict__ out_paths,
    int T, int N, int V, int rows) {
  const int lane = threadIdx.x & (WAVE - 1);
  const int w    = threadIdx.x >> 6;
  const int row  = blockIdx.x * 4 + w;
  const bool active = row < rows;
  const float* p = logits + (size_t)(active ? row : 0) * V;

  float m = -3.4e38f; int mi = 0;
  for (int i = lane; i < V; i += WAVE) {
    const float x = p[i];
    if (x > m) { m = x; mi = i; }
  }
  for (int off = 32; off; off >>= 1) {
    const float om = __shfl_down(m, off);
    const int   oi = __shfl_down(mi, off);
    if (om > m || (om == m && oi < mi)) { m = om; mi = oi; }
  }
  m = __shfl(m, 0);
  float s = 0.f;
  for (int i = lane; i < V; i += WAVE) s += __expf(p[i] - m);
  for (int off = 32; off; off >>= 1) s += __shfl_down(s, off);

  __shared__ float s_path[4];
  if (lane == 0 && active) {
    const int t = row / N, n = row % N;
    rmaxT[(size_t)n * T + t] = -__logf(s);
    rargT[(size_t)n * T + t] = mi;
    s_path[w] = (float)mi;
  }
  __syncthreads();
  if (threadIdx.x < 4) {
    const int r = blockIdx.x * 4 + threadIdx.x;
    if (r < rows) out_paths[r] = s_path[threadIdx.x];
  }
}

// ---------------- Kernel 2: per-n dedup + compaction + sums ------------------
// Default path values were already written by kernel 1; this kernel computes
// keep flags, the block scan, the two per-n scalars, and scatters only the
// kept tokens over the compacted prefix (masked_scatter_ semantics).
#define CB 256
__global__ __launch_bounds__(CB) void ctc_compact_kernel(
    const float* __restrict__ rmaxT, const int* __restrict__ rargT,
    const int* __restrict__ in_lens, float* __restrict__ out,
    int T, int N, int V) {
  const int n = blockIdx.x;
  const int tid = threadIdx.x;
  const int L = in_lens[n];
  const int blank = V - 1;            // (-1 + V) % V
  const int items = (T + CB - 1) / CB;
  const int t0 = tid * items;

  float* out_total = out;
  float* out_paths = out + N;                    // (T, N) layout
  float* out_lens  = out + N + (size_t)T * N;

  const float* rm = rmaxT + (size_t)n * T;
  const int*   ra = rargT + (size_t)n * T;

  int   cnt = 0;
  float sum = 0.f;
  int prev = (t0 > 0 && t0 <= T) ? ra[t0 - 1] : -1;
  for (int i = 0; i < items; ++i) {
    const int t = t0 + i;
    if (t >= T) break;
    const int a = ra[t];
    const bool keep = (t < L) && (a != blank) && (t == 0 || a != prev);
    prev = a;
    cnt += keep ? 1 : 0;
    if (t < L) sum += rm[t];
  }

  __shared__ int   s_cnt[CB];
  __shared__ float s_sum[CB];
  s_cnt[tid] = cnt;
  s_sum[tid] = sum;
  __syncthreads();
  // inclusive Hillis-Steele scan (cnt) / reduction (sum rides along)
  for (int off = 1; off < CB; off <<= 1) {
    const int   c  = (tid >= off) ? s_cnt[tid - off] : 0;
    const float sv = (tid >= off) ? s_sum[tid - off] : 0.f;
    __syncthreads();
    s_cnt[tid] += c;
    s_sum[tid] += sv;
    __syncthreads();
  }
  const int prefix = s_cnt[tid] - cnt;           // exclusive
  if (tid == 0) {
    out_total[n] = s_sum[CB - 1];
    out_lens[n]  = (float)s_cnt[CB - 1];
  }

  // scatter kept tokens into compacted prefix (overwrites kernel-1 defaults;
  // cross-kernel ordering on the stream guarantees kernel 1 finished)
  int pos = prefix;
  prev = (t0 > 0 && t0 <= T) ? ra[t0 - 1] : -1;
  for (int i = 0; i < items; ++i) {
    const int t = t0 + i;
    if (t >= T) break;
    const int a = ra[t];
    const bool keep = (t < L) && (a != blank) && (t == 0 || a != prev);
    prev = a;
    if (keep) {
      out_paths[(size_t)pos * N + n] = (float)a;
      ++pos;
    }
  }
}

extern "C" void kernel_launch(void* const* d_in, const int* in_sizes, int n_in,
                              void* d_out, int out_size, void* d_ws, size_t ws_size,
                              hipStream_t stream) {
  const float* logits = (const float*)d_in[0];
  const int* in_lens  = (const int*)d_in[1];
  float* out = (float*)d_out;

  const int N = in_sizes[1];
  const int T = (out_size - 2 * N) / N;          // out = N + T*N + N
  const long long total = in_sizes[0];
  const int V = (int)(total / ((long long)T * N));
  const int rows = T * N;

  float* rmaxT = (float*)d_ws;
  int*   rargT = (int*)((char*)d_ws + (size_t)rows * sizeof(float));
  float* out_paths = out + N;

  const int grid1 = (rows + 3) / 4;              // 4 waves (rows) per block

  if (V == 1024) {
    row_lse_kernel<4><<<grid1, 256, 0, stream>>>(logits, rmaxT, rargT, out_paths, T, N, rows);
  } else if (V == 512) {
    row_lse_kernel<2><<<grid1, 256, 0, stream>>>(logits, rmaxT, rargT, out_paths, T, N, rows);
  } else if (V == 2048) {
    row_lse_kernel<8><<<grid1, 256, 0, stream>>>(logits, rmaxT, rargT, out_paths, T, N, rows);
  } else {
    row_lse_generic<<<grid1, 256, 0, stream>>>(logits, rmaxT, rargT, out_paths, T, N, V, rows);
  }

  ctc_compact_kernel<<<N, CB, 0, stream>>>(rmaxT, rargT, in_lens, out, T, N, V);
}